// Round 1
// baseline (2020.909 us; speedup 1.0000x reference)
//
#include <hip/hip_runtime.h>

// CrossRQVAE forward, fp32-faithful everywhere (argmin precision chain).
// Pipeline: enc L0..L3 (GEMM+bias+ReLU) -> VQ step x3 (reg-resident codebook)
//           -> dec D0..D3 -> outputs {out, rq_loss, indices(float), one_hots, logits}.

static constexpr int BATCH = 32768;

// output offsets (floats)
static constexpr long long OFF_LOSS = 33554432LL;                // 32768*1024
static constexpr long long OFF_IDX  = OFF_LOSS + 1;              // 33554433
static constexpr long long OFF_OH   = OFF_IDX + 32768LL*3;       // 33652737
static constexpr long long OFF_LG   = OFF_OH + 32768LL*3*256;    // 58818561

// ---------------- fp32 tiled GEMM: C[M,N] = A[M,K] @ W[N,K]^T + bias, opt ReLU ----
template<int BM, int BN, int BK, int TM, int TN, bool RELU>
__global__ __launch_bounds__(256) void gemm_bias_k(
    const float* __restrict__ A, const float* __restrict__ W,
    const float* __restrict__ bias, float* __restrict__ C,
    int M, int N, int K)
{
    static_assert((BM/TM)*(BN/TN) == 256, "block must be 256 threads");
    __shared__ float As[BK][BM];
    __shared__ float Ws[BK][BN];
    const int t  = threadIdx.x;
    const int tx = t % (BN/TN);
    const int ty = t / (BN/TN);
    const int m0 = blockIdx.y * BM;
    const int n0 = blockIdx.x * BN;

    float acc[TM][TN] = {};

    for (int k0 = 0; k0 < K; k0 += BK) {
        for (int i = t; i < BM*BK/4; i += 256) {
            const int r  = i / (BK/4);
            const int c4 = (i % (BK/4)) * 4;
            const float4 v = *reinterpret_cast<const float4*>(A + (size_t)(m0+r)*K + k0 + c4);
            As[c4+0][r] = v.x; As[c4+1][r] = v.y; As[c4+2][r] = v.z; As[c4+3][r] = v.w;
        }
        for (int i = t; i < BN*BK/4; i += 256) {
            const int r  = i / (BK/4);
            const int c4 = (i % (BK/4)) * 4;
            const float4 v = *reinterpret_cast<const float4*>(W + (size_t)(n0+r)*K + k0 + c4);
            Ws[c4+0][r] = v.x; Ws[c4+1][r] = v.y; Ws[c4+2][r] = v.z; Ws[c4+3][r] = v.w;
        }
        __syncthreads();
        #pragma unroll
        for (int k = 0; k < BK; ++k) {
            float ra[TM], rw[TN];
            #pragma unroll
            for (int i = 0; i < TM; ++i) ra[i] = As[k][ty*TM+i];
            #pragma unroll
            for (int j = 0; j < TN; ++j) rw[j] = Ws[k][tx*TN+j];
            #pragma unroll
            for (int i = 0; i < TM; ++i)
                #pragma unroll
                for (int j = 0; j < TN; ++j)
                    acc[i][j] = fmaf(ra[i], rw[j], acc[i][j]);
        }
        __syncthreads();
    }
    #pragma unroll
    for (int i = 0; i < TM; ++i) {
        const size_t m = (size_t)(m0 + ty*TM + i);
        #pragma unroll
        for (int j = 0; j < TN; ++j) {
            const int n = n0 + tx*TN + j;
            float v = acc[i][j] + bias[n];
            if (RELU) v = fmaxf(v, 0.0f);
            C[m*(size_t)N + n] = v;
        }
    }
}

// ---------------- VQ step: one wave per row, 4 codes/lane in registers ----------
template<int Q, bool INIT>
__global__ __launch_bounds__(256) void vq_step_k(
    float* __restrict__ resid,          // [B,32] in/out (in-place residual)
    const float* __restrict__ cb,       // [256,32]
    float* __restrict__ xq,             // [B,32] accumulated straight-through value
    float* __restrict__ o_idx,          // [B,3] (float-encoded ints)
    float* __restrict__ o_oh,           // [B,3,256]
    float* __restrict__ o_lg,           // [B,3,256]
    float* __restrict__ loss_accum)     // 1 float
{
    const int lane = threadIdx.x & 63;
    const int wid  = blockIdx.x * (blockDim.x >> 6) + (threadIdx.x >> 6);
    const int nw   = gridDim.x * (blockDim.x >> 6);

    // this lane's 4 codebook rows (c = lane + 64*m), kept in VGPRs for the whole kernel
    float creg[4][32];
    float csq[4];
    #pragma unroll
    for (int m = 0; m < 4; ++m) {
        const int c = lane + 64*m;
        float s = 0.f;
        #pragma unroll
        for (int k = 0; k < 32; ++k) { const float v = cb[(size_t)c*32 + k]; creg[m][k] = v; s = fmaf(v, v, s); }
        csq[m] = s;
    }

    float lsum = 0.f;
    for (int b = wid; b < BATCH; b += nw) {
        const float rv = resid[(size_t)b*32 + (lane & 31)];
        float rr[32];
        #pragma unroll
        for (int k = 0; k < 32; ++k) rr[k] = __shfl(rv, k);   // row residual broadcast
        float ssl = 0.f;
        #pragma unroll
        for (int k = 0; k < 32; ++k) ssl = fmaf(rr[k], rr[k], ssl);

        float d[4];
        #pragma unroll
        for (int m = 0; m < 4; ++m) {
            float dot = 0.f;
            #pragma unroll
            for (int k = 0; k < 32; ++k) dot = fmaf(rr[k], creg[m][k], dot);
            d[m] = ssl + csq[m] - 2.0f*dot;
        }
        // local argmin (ascending c => strict < keeps lowest index, matching np.argmin)
        float bd = d[0]; int bi = lane;
        #pragma unroll
        for (int m = 1; m < 4; ++m) {
            const int c = lane + 64*m;
            if (d[m] < bd) { bd = d[m]; bi = c; }
        }
        #pragma unroll
        for (int off = 32; off > 0; off >>= 1) {
            const float od = __shfl_xor(bd, off);
            const int   oi = __shfl_xor(bi, off);
            if (od < bd || (od == bd && oi < bi)) { bd = od; bi = oi; }
        }

        const size_t ob = (size_t)b*768 + (size_t)Q*256;
        #pragma unroll
        for (int m = 0; m < 4; ++m) {
            const int c = lane + 64*m;
            o_lg[ob + c] = d[m];
            o_oh[ob + c] = (c == bi) ? 1.0f : 0.0f;
        }
        if (lane == 0) o_idx[(size_t)b*3 + Q] = (float)bi;

        // straight-through value, replicating jax fp32 op order: r + (x_q - r)
        const float xqk  = cb[(size_t)bi*32 + (lane & 31)];
        const float diff = xqk - rv;               // x_q - latent (raw, for loss)
        const float xres = rv + (xqk - rv);        // x_q_st
        if (lane < 32) {
            resid[(size_t)b*32 + lane] = rv - xres;
            if (INIT) xq[(size_t)b*32 + lane] = xres;
            else      xq[(size_t)b*32 + lane] += xres;
            lsum = fmaf(diff, diff, lsum);
        }
    }
    #pragma unroll
    for (int off = 32; off > 0; off >>= 1) lsum += __shfl_xor(lsum, off);
    if (lane == 0) atomicAdd(loss_accum, lsum);
}

__global__ void zero_loss_k(float* p) { if (threadIdx.x == 0) p[0] = 0.f; }
__global__ void finalize_loss_k(const float* __restrict__ p, float* __restrict__ o) {
    // rq_loss = mean_q[(1+BETA)*mean(diff^2)] = 1.25 * S / (3*B*32)
    if (threadIdx.x == 0) o[0] = 1.25f * p[0] / (3.0f * 32768.0f * 32.0f);
}

extern "C" void kernel_launch(void* const* d_in, const int* in_sizes, int n_in,
                              void* d_out, int out_size, void* d_ws, size_t ws_size,
                              hipStream_t stream)
{
    const float* x     = (const float*)d_in[0];
    const float* ew[4] = {(const float*)d_in[1], (const float*)d_in[3], (const float*)d_in[5], (const float*)d_in[7]};
    const float* eb[4] = {(const float*)d_in[2], (const float*)d_in[4], (const float*)d_in[6], (const float*)d_in[8]};
    const float* dw[4] = {(const float*)d_in[9], (const float*)d_in[11], (const float*)d_in[13], (const float*)d_in[15]};
    const float* db[4] = {(const float*)d_in[10], (const float*)d_in[12], (const float*)d_in[14], (const float*)d_in[16]};
    const float* cb[3] = {(const float*)d_in[17], (const float*)d_in[18], (const float*)d_in[19]};

    float* ws   = (float*)d_ws;
    float* h0   = ws;               // 32768*512
    float* h1   = ws + 16777216;    // 32768*256
    float* h2   = ws + 25165824;    // 32768*128
    float* lat  = ws + 29360128;    // 32768*32  (becomes residual in-place)
    float* xq   = ws + 30408704;    // 32768*32
    float* loss = ws + 31457280;    // 1

    float* out    = (float*)d_out;
    float* o_loss = out + OFF_LOSS;
    float* o_idx  = out + OFF_IDX;
    float* o_oh   = out + OFF_OH;
    float* o_lg   = out + OFF_LG;

    const int M = BATCH;
    dim3 blk(256);

    zero_loss_k<<<dim3(1), dim3(64), 0, stream>>>(loss);

    // encoder
    gemm_bias_k<128,64,32,8,4,true ><<<dim3(512/64,  M/128), blk, 0, stream>>>(x,  ew[0], eb[0], h0,  M, 512, 1024);
    gemm_bias_k<128,64,32,8,4,true ><<<dim3(256/64,  M/128), blk, 0, stream>>>(h0, ew[1], eb[1], h1,  M, 256, 512);
    gemm_bias_k<128,64,32,8,4,true ><<<dim3(128/64,  M/128), blk, 0, stream>>>(h1, ew[2], eb[2], h2,  M, 128, 256);
    gemm_bias_k<128,32,32,8,2,false><<<dim3(32/32,   M/128), blk, 0, stream>>>(h2, ew[3], eb[3], lat, M, 32,  128);

    // residual VQ (3 sequential steps; residual updated in-place in `lat`)
    vq_step_k<0,true ><<<dim3(2048), blk, 0, stream>>>(lat, cb[0], xq, o_idx, o_oh, o_lg, loss);
    vq_step_k<1,false><<<dim3(2048), blk, 0, stream>>>(lat, cb[1], xq, o_idx, o_oh, o_lg, loss);
    vq_step_k<2,false><<<dim3(2048), blk, 0, stream>>>(lat, cb[2], xq, o_idx, o_oh, o_lg, loss);

    finalize_loss_k<<<dim3(1), dim3(64), 0, stream>>>(loss, o_loss);

    // decoder
    gemm_bias_k<128,64,32,8,4,true ><<<dim3(128/64,  M/128), blk, 0, stream>>>(xq, dw[0], db[0], h2,  M, 128, 32);
    gemm_bias_k<128,64,32,8,4,true ><<<dim3(256/64,  M/128), blk, 0, stream>>>(h2, dw[1], db[1], h1,  M, 256, 128);
    gemm_bias_k<128,64,32,8,4,true ><<<dim3(512/64,  M/128), blk, 0, stream>>>(h1, dw[2], db[2], h0,  M, 512, 256);
    gemm_bias_k<128,64,32,8,4,false><<<dim3(1024/64, M/128), blk, 0, stream>>>(h0, dw[3], db[3], out, M, 1024, 512);
}

// Round 2
// 1433.778 us; speedup vs baseline: 1.4095x; 1.4095x over previous
//
#include <hip/hip_runtime.h>
#include <hip/hip_bf16.h>

// CrossRQVAE forward.
// Encoder: fp32 tiled GEMM (exact same k-summation order as round-1 -> argmin-stable).
// VQ: reg-resident codebook, unchanged (+ bf16 xq output for decoder).
// Decoder: bf16 MFMA GEMM (m97 structure: 128^2 tile, BK=32, global_load_lds w16).

static constexpr int BATCH = 32768;

static constexpr long long OFF_LOSS = 33554432LL;                // 32768*1024
static constexpr long long OFF_IDX  = OFF_LOSS + 1;
static constexpr long long OFF_OH   = OFF_IDX + 32768LL*3;
static constexpr long long OFF_LG   = OFF_OH + 32768LL*3*256;

using bf16x8 = __attribute__((ext_vector_type(8))) __bf16;
using f32x4  = __attribute__((ext_vector_type(4))) float;

__device__ __forceinline__ void gload_lds16(const void* g, void* l) {
    __builtin_amdgcn_global_load_lds(
        (const __attribute__((address_space(1))) void*)g,
        (__attribute__((address_space(3))) void*)l, 16, 0, 0);
}

// ---------------- fp32 GEMM, 128x128 tile, BK=16, 8x8/thread ----------------
// C[M,N] = A[M,K] @ W[N,K]^T + bias (+ReLU). Sequential-k accumulation (bit-stable).
template<bool RELU>
__global__ __launch_bounds__(256) void gemm_f32_k(
    const float* __restrict__ A, const float* __restrict__ W,
    const float* __restrict__ bias, float* __restrict__ C,
    int M, int N, int K)
{
    __shared__ __align__(16) float As[16][132];
    __shared__ __align__(16) float Bs[16][132];
    const int t  = threadIdx.x;
    const int tx = t & 15;          // N-dir
    const int ty = t >> 4;          // M-dir
    const int m0 = blockIdx.y * 128;
    const int n0 = blockIdx.x * 128;

    float acc[8][8] = {};

    for (int k0 = 0; k0 < K; k0 += 16) {
        __syncthreads();
        #pragma unroll
        for (int h = 0; h < 2; ++h) {
            const int c  = t + h*256;        // 0..511
            const int r  = c >> 2;           // 0..127
            const int k4 = (c & 3) * 4;      // 0,4,8,12
            const float4 va = *reinterpret_cast<const float4*>(A + (size_t)(m0+r)*K + k0 + k4);
            As[k4+0][r] = va.x; As[k4+1][r] = va.y; As[k4+2][r] = va.z; As[k4+3][r] = va.w;
            const float4 vb = *reinterpret_cast<const float4*>(W + (size_t)(n0+r)*K + k0 + k4);
            Bs[k4+0][r] = vb.x; Bs[k4+1][r] = vb.y; Bs[k4+2][r] = vb.z; Bs[k4+3][r] = vb.w;
        }
        __syncthreads();
        #pragma unroll
        for (int k = 0; k < 16; ++k) {
            const float4 a0 = *reinterpret_cast<const float4*>(&As[k][ty*8]);
            const float4 a1 = *reinterpret_cast<const float4*>(&As[k][ty*8+4]);
            const float4 b0 = *reinterpret_cast<const float4*>(&Bs[k][tx*8]);
            const float4 b1 = *reinterpret_cast<const float4*>(&Bs[k][tx*8+4]);
            const float ra[8] = {a0.x,a0.y,a0.z,a0.w,a1.x,a1.y,a1.z,a1.w};
            const float rb[8] = {b0.x,b0.y,b0.z,b0.w,b1.x,b1.y,b1.z,b1.w};
            #pragma unroll
            for (int i = 0; i < 8; ++i)
                #pragma unroll
                for (int j = 0; j < 8; ++j)
                    acc[i][j] = fmaf(ra[i], rb[j], acc[i][j]);
        }
    }
    float bv[8];
    #pragma unroll
    for (int j = 0; j < 8; ++j) bv[j] = bias[n0 + tx*8 + j];
    #pragma unroll
    for (int i = 0; i < 8; ++i) {
        const size_t row = (size_t)(m0 + ty*8 + i);
        float4 v0, v1;
        float o[8];
        #pragma unroll
        for (int j = 0; j < 8; ++j) {
            float v = acc[i][j] + bv[j];
            if (RELU) v = fmaxf(v, 0.0f);
            o[j] = v;
        }
        v0.x=o[0]; v0.y=o[1]; v0.z=o[2]; v0.w=o[3];
        v1.x=o[4]; v1.y=o[5]; v1.z=o[6]; v1.w=o[7];
        *reinterpret_cast<float4*>(C + row*(size_t)N + n0 + tx*8)     = v0;
        *reinterpret_cast<float4*>(C + row*(size_t)N + n0 + tx*8 + 4) = v1;
    }
}

// ---------------- legacy small fp32 GEMM (enc L3, N=32) --------------------
template<int BM, int BN, int BK, int TM, int TN, bool RELU>
__global__ __launch_bounds__(256) void gemm_bias_k(
    const float* __restrict__ A, const float* __restrict__ W,
    const float* __restrict__ bias, float* __restrict__ C,
    int M, int N, int K)
{
    __shared__ float As[BK][BM];
    __shared__ float Ws[BK][BN];
    const int t  = threadIdx.x;
    const int tx = t % (BN/TN);
    const int ty = t / (BN/TN);
    const int m0 = blockIdx.y * BM;
    const int n0 = blockIdx.x * BN;
    float acc[TM][TN] = {};
    for (int k0 = 0; k0 < K; k0 += BK) {
        for (int i = t; i < BM*BK/4; i += 256) {
            const int r  = i / (BK/4);
            const int c4 = (i % (BK/4)) * 4;
            const float4 v = *reinterpret_cast<const float4*>(A + (size_t)(m0+r)*K + k0 + c4);
            As[c4+0][r] = v.x; As[c4+1][r] = v.y; As[c4+2][r] = v.z; As[c4+3][r] = v.w;
        }
        for (int i = t; i < BN*BK/4; i += 256) {
            const int r  = i / (BK/4);
            const int c4 = (i % (BK/4)) * 4;
            const float4 v = *reinterpret_cast<const float4*>(W + (size_t)(n0+r)*K + k0 + c4);
            Ws[c4+0][r] = v.x; Ws[c4+1][r] = v.y; Ws[c4+2][r] = v.z; Ws[c4+3][r] = v.w;
        }
        __syncthreads();
        #pragma unroll
        for (int k = 0; k < BK; ++k) {
            float ra[TM], rw[TN];
            #pragma unroll
            for (int i = 0; i < TM; ++i) ra[i] = As[k][ty*TM+i];
            #pragma unroll
            for (int j = 0; j < TN; ++j) rw[j] = Ws[k][tx*TN+j];
            #pragma unroll
            for (int i = 0; i < TM; ++i)
                #pragma unroll
                for (int j = 0; j < TN; ++j)
                    acc[i][j] = fmaf(ra[i], rw[j], acc[i][j]);
        }
        __syncthreads();
    }
    #pragma unroll
    for (int i = 0; i < TM; ++i) {
        const size_t m = (size_t)(m0 + ty*TM + i);
        #pragma unroll
        for (int j = 0; j < TN; ++j) {
            const int n = n0 + tx*TN + j;
            float v = acc[i][j] + bias[n];
            if (RELU) v = fmaxf(v, 0.0f);
            C[m*(size_t)N + n] = v;
        }
    }
}

// ---------------- bf16 MFMA GEMM (decoder), 128x128 tile, BK=32 -------------
template<bool RELU, bool OUTBF>
__global__ __launch_bounds__(256) void gemm_bf16_k(
    const __hip_bfloat16* __restrict__ A,   // [M,K]
    const __hip_bfloat16* __restrict__ W,   // [N,K]
    const float* __restrict__ bias,
    __hip_bfloat16* __restrict__ Cb, float* __restrict__ Cf,
    int M, int N, int K)
{
    __shared__ __align__(16) __hip_bfloat16 As[128*32];
    __shared__ __align__(16) __hip_bfloat16 Bs[128*32];
    const int t = threadIdx.x, lane = t & 63, w = t >> 6;
    const int m0 = blockIdx.y * 128, n0 = blockIdx.x * 128;
    const int wr = (w >> 1) * 64, wc = (w & 1) * 64;
    const int r15 = lane & 15, kg = lane >> 4;
    f32x4 acc[4][4] = {};

    for (int k0 = 0; k0 < K; k0 += 32) {
        __syncthreads();
        #pragma unroll
        for (int h = 0; h < 2; ++h) {
            const int c = h*256 + w*64 + lane;
            gload_lds16(A + (size_t)(m0 + (c>>2))*K + k0 + (c&3)*8,
                        (char*)As + (h*256 + w*64)*16);
            gload_lds16(W + (size_t)(n0 + (c>>2))*K + k0 + (c&3)*8,
                        (char*)Bs + (h*256 + w*64)*16);
        }
        __syncthreads();
        bf16x8 a[4], b[4];
        #pragma unroll
        for (int i = 0; i < 4; ++i)
            a[i] = *reinterpret_cast<const bf16x8*>((const char*)As + (wr + i*16 + r15)*64 + kg*16);
        #pragma unroll
        for (int j = 0; j < 4; ++j)
            b[j] = *reinterpret_cast<const bf16x8*>((const char*)Bs + (wc + j*16 + r15)*64 + kg*16);
        #pragma unroll
        for (int i = 0; i < 4; ++i)
            #pragma unroll
            for (int j = 0; j < 4; ++j)
                acc[i][j] = __builtin_amdgcn_mfma_f32_16x16x32_bf16(a[i], b[j], acc[i][j], 0, 0, 0);
    }
    const int rowb = kg * 4;
    #pragma unroll
    for (int i = 0; i < 4; ++i) {
        #pragma unroll
        for (int j = 0; j < 4; ++j) {
            const int col = n0 + wc + j*16 + r15;
            const float bv = bias[col];
            #pragma unroll
            for (int r = 0; r < 4; ++r) {
                const int row = m0 + wr + i*16 + rowb + r;
                float v = acc[i][j][r] + bv;
                if (RELU) v = fmaxf(v, 0.0f);
                if (OUTBF) Cb[(size_t)row*N + col] = __float2bfloat16(v);
                else       Cf[(size_t)row*N + col] = v;
            }
        }
    }
}

// ---------------- VQ step ---------------------------------------------------
template<int Q, bool INIT, bool FINAL>
__global__ __launch_bounds__(256) void vq_step_k(
    float* __restrict__ resid, const float* __restrict__ cb,
    float* __restrict__ xq, __hip_bfloat16* __restrict__ xq16,
    float* __restrict__ o_idx, float* __restrict__ o_oh,
    float* __restrict__ o_lg, float* __restrict__ loss_accum)
{
    const int lane = threadIdx.x & 63;
    const int wid  = blockIdx.x * (blockDim.x >> 6) + (threadIdx.x >> 6);
    const int nw   = gridDim.x * (blockDim.x >> 6);

    float creg[4][32];
    float csq[4];
    #pragma unroll
    for (int m = 0; m < 4; ++m) {
        const int c = lane + 64*m;
        float s = 0.f;
        #pragma unroll
        for (int k = 0; k < 32; ++k) { const float v = cb[(size_t)c*32 + k]; creg[m][k] = v; s = fmaf(v, v, s); }
        csq[m] = s;
    }

    float lsum = 0.f;
    for (int b = wid; b < BATCH; b += nw) {
        const float rv = resid[(size_t)b*32 + (lane & 31)];
        float rr[32];
        #pragma unroll
        for (int k = 0; k < 32; ++k) rr[k] = __shfl(rv, k);
        float ssl = 0.f;
        #pragma unroll
        for (int k = 0; k < 32; ++k) ssl = fmaf(rr[k], rr[k], ssl);

        float d[4];
        #pragma unroll
        for (int m = 0; m < 4; ++m) {
            float dot = 0.f;
            #pragma unroll
            for (int k = 0; k < 32; ++k) dot = fmaf(rr[k], creg[m][k], dot);
            d[m] = ssl + csq[m] - 2.0f*dot;
        }
        float bd = d[0]; int bi = lane;
        #pragma unroll
        for (int m = 1; m < 4; ++m) {
            const int c = lane + 64*m;
            if (d[m] < bd) { bd = d[m]; bi = c; }
        }
        #pragma unroll
        for (int off = 32; off > 0; off >>= 1) {
            const float od = __shfl_xor(bd, off);
            const int   oi = __shfl_xor(bi, off);
            if (od < bd || (od == bd && oi < bi)) { bd = od; bi = oi; }
        }

        const size_t ob = (size_t)b*768 + (size_t)Q*256;
        #pragma unroll
        for (int m = 0; m < 4; ++m) {
            const int c = lane + 64*m;
            o_lg[ob + c] = d[m];
            o_oh[ob + c] = (c == bi) ? 1.0f : 0.0f;
        }
        if (lane == 0) o_idx[(size_t)b*3 + Q] = (float)bi;

        const float xqk  = cb[(size_t)bi*32 + (lane & 31)];
        const float diff = xqk - rv;
        const float xres = rv + (xqk - rv);
        if (lane < 32) {
            resid[(size_t)b*32 + lane] = rv - xres;
            float xnew = INIT ? xres : (xq[(size_t)b*32 + lane] + xres);
            xq[(size_t)b*32 + lane] = xnew;
            if (FINAL) xq16[(size_t)b*32 + lane] = __float2bfloat16(xnew);
            lsum = fmaf(diff, diff, lsum);
        }
    }
    #pragma unroll
    for (int off = 32; off > 0; off >>= 1) lsum += __shfl_xor(lsum, off);
    if (lane == 0) atomicAdd(loss_accum, lsum);
}

__global__ void zero_loss_k(float* p) { if (threadIdx.x == 0) p[0] = 0.f; }
__global__ void finalize_loss_k(const float* __restrict__ p, float* __restrict__ o) {
    if (threadIdx.x == 0) o[0] = 1.25f * p[0] / (3.0f * 32768.0f * 32.0f);
}

__global__ void f2b_k(const float* __restrict__ s, __hip_bfloat16* __restrict__ d, int n) {
    int i = blockIdx.x * blockDim.x + threadIdx.x;
    if (i < n) d[i] = __float2bfloat16(s[i]);
}

extern "C" void kernel_launch(void* const* d_in, const int* in_sizes, int n_in,
                              void* d_out, int out_size, void* d_ws, size_t ws_size,
                              hipStream_t stream)
{
    const float* x     = (const float*)d_in[0];
    const float* ew[4] = {(const float*)d_in[1], (const float*)d_in[3], (const float*)d_in[5], (const float*)d_in[7]};
    const float* eb[4] = {(const float*)d_in[2], (const float*)d_in[4], (const float*)d_in[6], (const float*)d_in[8]};
    const float* dw[4] = {(const float*)d_in[9], (const float*)d_in[11], (const float*)d_in[13], (const float*)d_in[15]};
    const float* db[4] = {(const float*)d_in[10], (const float*)d_in[12], (const float*)d_in[14], (const float*)d_in[16]};
    const float* cb[3] = {(const float*)d_in[17], (const float*)d_in[18], (const float*)d_in[19]};

    float* ws   = (float*)d_ws;
    float* h0   = ws;               // 32768*512 f32  (reused as bf16 arena for decoder)
    float* h1   = ws + 16777216;    // 32768*256 f32
    float* h2   = ws + 25165824;    // 32768*128 f32
    float* lat  = ws + 29360128;    // 32768*32
    float* xq   = ws + 30408704;    // 32768*32
    float* loss = ws + 31457280;

    // bf16 arena inside the (dead-after-encoder) h0 region
    __hip_bfloat16* bw   = (__hip_bfloat16*)d_ws;
    __hip_bfloat16* xq16 = bw;                 // 1048576
    __hip_bfloat16* wd0b = bw + 1048576;       // 4096
    __hip_bfloat16* wd1b = bw + 1052672;       // 32768
    __hip_bfloat16* wd2b = bw + 1085440;       // 131072
    __hip_bfloat16* wd3b = bw + 1216512;       // 524288
    __hip_bfloat16* h2b  = bw + 1740800;       // 4194304
    __hip_bfloat16* h1b  = bw + 5935104;       // 8388608
    __hip_bfloat16* h0b  = bw + 14323712;      // 16777216  (ends < h1 f32 region)

    float* out    = (float*)d_out;
    float* o_loss = out + OFF_LOSS;
    float* o_idx  = out + OFF_IDX;
    float* o_oh   = out + OFF_OH;
    float* o_lg   = out + OFF_LG;

    const int M = BATCH;
    dim3 blk(256);

    zero_loss_k<<<dim3(1), dim3(64), 0, stream>>>(loss);

    // encoder (fp32, bit-stable k-order)
    gemm_f32_k<true><<<dim3(4, M/128), blk, 0, stream>>>(x,  ew[0], eb[0], h0, M, 512, 1024);
    gemm_f32_k<true><<<dim3(2, M/128), blk, 0, stream>>>(h0, ew[1], eb[1], h1, M, 256, 512);
    gemm_f32_k<true><<<dim3(1, M/128), blk, 0, stream>>>(h1, ew[2], eb[2], h2, M, 128, 256);
    gemm_bias_k<128,32,32,8,2,false><<<dim3(1, M/128), blk, 0, stream>>>(h2, ew[3], eb[3], lat, M, 32, 128);

    // residual VQ
    vq_step_k<0,true ,false><<<dim3(2048), blk, 0, stream>>>(lat, cb[0], xq, nullptr, o_idx, o_oh, o_lg, loss);
    vq_step_k<1,false,false><<<dim3(2048), blk, 0, stream>>>(lat, cb[1], xq, nullptr, o_idx, o_oh, o_lg, loss);
    vq_step_k<2,false,true ><<<dim3(2048), blk, 0, stream>>>(lat, cb[2], xq, xq16,    o_idx, o_oh, o_lg, loss);

    finalize_loss_k<<<dim3(1), dim3(64), 0, stream>>>(loss, o_loss);

    // decoder weights -> bf16 (h0 fp32 is dead from here on)
    f2b_k<<<dim3(16),   blk, 0, stream>>>(dw[0], wd0b, 4096);
    f2b_k<<<dim3(128),  blk, 0, stream>>>(dw[1], wd1b, 32768);
    f2b_k<<<dim3(512),  blk, 0, stream>>>(dw[2], wd2b, 131072);
    f2b_k<<<dim3(2048), blk, 0, stream>>>(dw[3], wd3b, 524288);

    // decoder (bf16 MFMA)
    gemm_bf16_k<true ,true ><<<dim3(1, M/128), blk, 0, stream>>>(xq16, wd0b, db[0], h2b, nullptr, M, 128,  32);
    gemm_bf16_k<true ,true ><<<dim3(2, M/128), blk, 0, stream>>>(h2b,  wd1b, db[1], h1b, nullptr, M, 256,  128);
    gemm_bf16_k<true ,true ><<<dim3(4, M/128), blk, 0, stream>>>(h1b,  wd2b, db[2], h0b, nullptr, M, 512,  256);
    gemm_bf16_k<false,false><<<dim3(8, M/128), blk, 0, stream>>>(h0b,  wd3b, db[3], nullptr, out, M, 1024, 512);
}